// Round 1
// baseline (720.568 us; speedup 1.0000x reference)
//
#include <hip/hip_runtime.h>
#include <hip/hip_bf16.h>

#define IN_F   4096
#define OUT_F  4096
#define BM     128
#define BN     128
#define BK     64      // == GROUP_SIZE: one scale/zero per staged B row-slice
#define SA     72      // 64 + 8 bf16 pad: 144 B row stride, 16B-aligned, 2-way bank alias (free)
#define SB     72

typedef __bf16 bf16;
typedef __attribute__((ext_vector_type(8))) __bf16 bf16x8;
typedef __attribute__((ext_vector_type(4))) __bf16 bf16x4;
typedef __attribute__((ext_vector_type(4))) float floatx4;

__global__ __launch_bounds__(256) void hqq_gemm_kernel(
    const float* __restrict__ x,      // (M, IN_F) fp32
    const int*   __restrict__ Wp,     // (OUT_F, IN_F/8) int32, 8 bits per element, LSB first
    const float* __restrict__ scale,  // (OUT_F*IN_F/64,)
    const float* __restrict__ zero,   // (OUT_F*IN_F/64,)
    const float* __restrict__ bias,   // (OUT_F,)
    float*       __restrict__ out)    // (M, OUT_F) fp32
{
    __shared__ __align__(16) bf16 asmem[BM * SA];
    __shared__ __align__(16) bf16 bsmem[BN * SB];

    const int t      = threadIdx.x;
    const int lane   = t & 63;
    const int wave   = t >> 6;        // 0..3
    const int lane16 = lane & 15;
    const int kq     = lane >> 4;     // 0..3
    const int wm     = wave >> 1;     // wave row (0..1) -> 64 rows each
    const int wn     = wave & 1;      // wave col (0..1) -> 64 cols each

    const int n0 = blockIdx.x * BN;
    const int m0 = blockIdx.y * BM;

    floatx4 acc[4][4];
#pragma unroll
    for (int i = 0; i < 4; ++i)
#pragma unroll
        for (int j = 0; j < 4; ++j)
            acc[i][j] = (floatx4){0.f, 0.f, 0.f, 0.f};

    // A staging mapping: 256 threads cover 16 rows x 16 float4-cols per pass, 8 passes
    const int a_col4 = t & 15;   // float4 column within 64-wide k slice
    const int a_row0 = t >> 4;   // 0..15
    // B staging mapping: 2 threads per weight row, each unpacks 4 int32 (32 bits)
    const int b_nl   = t >> 1;   // 0..127 local n
    const int b_half = t & 1;    // which 32-bit-half of the 64-wide k slice

    for (int kt = 0; kt < IN_F / BK; ++kt) {
        // ---- stage A: fp32 -> bf16 into LDS ----
        const float* xp = x + (size_t)(m0 + a_row0) * IN_F + kt * BK + a_col4 * 4;
#pragma unroll
        for (int p = 0; p < 8; ++p) {
            float4 v = *(const float4*)(xp + (size_t)(p * 16) * IN_F);
            bf16x4 b = { (bf16)v.x, (bf16)v.y, (bf16)v.z, (bf16)v.w };
            *(bf16x4*)&asmem[(a_row0 + p * 16) * SA + a_col4 * 4] = b;
        }
        // ---- stage B: unpack 1-bit + dequant -> bf16 into LDS ----
        {
            const int4 v = *(const int4*)(Wp + (size_t)(n0 + b_nl) * (IN_F / 8)
                                          + kt * 8 + b_half * 4);
            const int g = (n0 + b_nl) * (IN_F / 64) + kt;   // group index
            const float sc = scale[g];
            const float zp = zero[g];
            const bf16 hi = (bf16)((1.0f - zp) * sc);
            const bf16 lo = (bf16)((0.0f - zp) * sc);
            const int vals[4] = {v.x, v.y, v.z, v.w};
#pragma unroll
            for (int e = 0; e < 4; ++e) {
                bf16x8 w;
#pragma unroll
                for (int j = 0; j < 8; ++j)
                    w[j] = ((vals[e] >> j) & 1) ? hi : lo;
                *(bf16x8*)&bsmem[b_nl * SB + b_half * 32 + e * 8] = w;
            }
        }
        __syncthreads();

        // ---- MFMA: 2 k-steps of 32, 4x4 tiles of 16x16 per wave ----
#pragma unroll
        for (int ks = 0; ks < 2; ++ks) {
            bf16x8 af[4], bfr[4];
#pragma unroll
            for (int i = 0; i < 4; ++i)
                af[i] = *(const bf16x8*)&asmem[(wm * 64 + i * 16 + lane16) * SA
                                               + ks * 32 + kq * 8];
#pragma unroll
            for (int j = 0; j < 4; ++j)
                bfr[j] = *(const bf16x8*)&bsmem[(wn * 64 + j * 16 + lane16) * SB
                                                + ks * 32 + kq * 8];
#pragma unroll
            for (int i = 0; i < 4; ++i)
#pragma unroll
                for (int j = 0; j < 4; ++j)
                    acc[i][j] = __builtin_amdgcn_mfma_f32_16x16x32_bf16(
                        af[i], bfr[j], acc[i][j], 0, 0, 0);
        }
        __syncthreads();
    }

    // ---- epilogue: C/D layout col=lane&15, row=(lane>>4)*4+r ----
#pragma unroll
    for (int j = 0; j < 4; ++j) {
        const int col = n0 + wn * 64 + j * 16 + lane16;
        const float bv = bias[col];
#pragma unroll
        for (int i = 0; i < 4; ++i) {
            const int row = m0 + wm * 64 + i * 16 + kq * 4;
#pragma unroll
            for (int r = 0; r < 4; ++r)
                out[(size_t)(row + r) * OUT_F + col] = acc[i][j][r] + bv;
        }
    }
}

extern "C" void kernel_launch(void* const* d_in, const int* in_sizes, int n_in,
                              void* d_out, int out_size, void* d_ws, size_t ws_size,
                              hipStream_t stream) {
    const float* x     = (const float*)d_in[0];
    const int*   Wp    = (const int*)d_in[1];
    const float* scale = (const float*)d_in[2];
    const float* zero  = (const float*)d_in[3];
    const float* bias  = (const float*)d_in[4];
    float*       out   = (float*)d_out;

    const int M = in_sizes[0] / IN_F;   // 8192
    dim3 grid(OUT_F / BN, M / BM);      // (32, 64)
    hqq_gemm_kernel<<<grid, 256, 0, stream>>>(x, Wp, scale, zero, bias, out);
}

// Round 2
// 523.185 us; speedup vs baseline: 1.3773x; 1.3773x over previous
//
#include <hip/hip_runtime.h>
#include <hip/hip_bf16.h>

#define IN_F   4096
#define OUT_F  4096

typedef __bf16 bf16;
typedef __attribute__((ext_vector_type(8))) __bf16 bf16x8;
typedef __attribute__((ext_vector_type(4))) __bf16 bf16x4;
typedef __attribute__((ext_vector_type(4))) float floatx4;

// ---------------------------------------------------------------------------
// Pre-pass 1: x fp32 -> bf16
// ---------------------------------------------------------------------------
__global__ __launch_bounds__(256) void convert_x_kernel(
    const float* __restrict__ x, bf16* __restrict__ xb)
{
    const size_t i = (size_t)blockIdx.x * 256 + threadIdx.x;   // one float4 each
    float4 v = ((const float4*)x)[i];
    bf16x4 b = { (bf16)v.x, (bf16)v.y, (bf16)v.z, (bf16)v.w };
    ((bf16x4*)xb)[i] = b;
}

// ---------------------------------------------------------------------------
// Pre-pass 2: unpack 1-bit + dequant -> bf16 W_hat (OUT_F, IN_F) row-major
// ---------------------------------------------------------------------------
__global__ __launch_bounds__(256) void dequant_w_kernel(
    const int* __restrict__ Wp, const float* __restrict__ scale,
    const float* __restrict__ zero, bf16* __restrict__ Wb)
{
    const int tid = blockIdx.x * 256 + threadIdx.x;   // 0 .. OUT_F*IN_F/8-1
    const int n = tid >> 9;                           // / (IN_F/8)
    const int b = tid & 511;
    const int g = (n << 6) + (b >> 3);                // group = n*64 + k/64
    const float sc = scale[g];
    const float zp = zero[g];
    const bf16 hi = (bf16)((1.0f - zp) * sc);
    const bf16 lo = (bf16)((0.0f - zp) * sc);
    const int v = Wp[tid];
    bf16x8 w;
#pragma unroll
    for (int j = 0; j < 8; ++j) w[j] = ((v >> j) & 1) ? hi : lo;
    *(bf16x8*)&Wb[(size_t)tid * 8] = w;
}

// ---------------------------------------------------------------------------
// Main GEMM: out(M,N) = A(M,K)bf16 @ B(N,K)bf16^T + bias, fp32 out
// m97 structure: 128x128x64 tiles, global_load_lds 16B staging, XOR-swizzled
// LDS (swizzle applied on the per-lane GLOBAL address so the wave-uniform
// base + lane*16 LDS contract is preserved).
// ---------------------------------------------------------------------------
__device__ __forceinline__ void gload_lds16(const void* g, void* l) {
    __builtin_amdgcn_global_load_lds(
        (const __attribute__((address_space(1))) unsigned int*)g,
        (__attribute__((address_space(3))) unsigned int*)l, 16, 0, 0);
}

__global__ __launch_bounds__(256) void bf16_gemm_bt_kernel(
    const bf16* __restrict__ A,     // (M, K) bf16
    const bf16* __restrict__ B,     // (N, K) bf16  (W_hat row-major)
    const float* __restrict__ bias, // (N,)
    float* __restrict__ out)        // (M, N) fp32
{
    __shared__ __align__(16) bf16 as[128 * 64];
    __shared__ __align__(16) bf16 bs[128 * 64];

    const int t      = threadIdx.x;
    const int lane   = t & 63;
    const int wave   = t >> 6;        // 0..3
    const int lane16 = lane & 15;
    const int kq     = lane >> 4;     // 0..3
    const int wm     = wave >> 1;
    const int wn     = wave & 1;

    const int n0 = blockIdx.x * 128;
    const int m0 = blockIdx.y * 128;

    floatx4 acc[4][4];
#pragma unroll
    for (int i = 0; i < 4; ++i)
#pragma unroll
        for (int j = 0; j < 4; ++j)
            acc[i][j] = (floatx4){0.f, 0.f, 0.f, 0.f};

    // staging: each wave covers 32 rows (4 issues x 8 rows); lane -> (row8, unit)
    const int srow8 = lane >> 3;      // row within 8-row issue
    const int sunit = lane & 7;       // 16B unit (8 bf16) within 64-wide row

    for (int kt = 0; kt < IN_F / 64; ++kt) {
#pragma unroll
        for (int i = 0; i < 4; ++i) {
            const int row   = wave * 32 + i * 8 + srow8;       // 0..127
            const int gunit = sunit ^ (row & 7);               // XOR swizzle
            gload_lds16(A + (size_t)(m0 + row) * IN_F + kt * 64 + gunit * 8,
                        &as[(wave * 32 + i * 8) * 64]);
            gload_lds16(B + (size_t)(n0 + row) * IN_F + kt * 64 + gunit * 8,
                        &bs[(wave * 32 + i * 8) * 64]);
        }
        __syncthreads();

#pragma unroll
        for (int ks = 0; ks < 2; ++ks) {
            const int u = ks * 4 + kq;          // 16B unit index within row
            bf16x8 af[4], bfr[4];
#pragma unroll
            for (int i = 0; i < 4; ++i) {
                const int r = wm * 64 + i * 16 + lane16;
                af[i] = *(const bf16x8*)&as[r * 64 + (u ^ (r & 7)) * 8];
            }
#pragma unroll
            for (int j = 0; j < 4; ++j) {
                const int r = wn * 64 + j * 16 + lane16;
                bfr[j] = *(const bf16x8*)&bs[r * 64 + (u ^ (r & 7)) * 8];
            }
#pragma unroll
            for (int i = 0; i < 4; ++i)
#pragma unroll
                for (int j = 0; j < 4; ++j)
                    acc[i][j] = __builtin_amdgcn_mfma_f32_16x16x32_bf16(
                        af[i], bfr[j], acc[i][j], 0, 0, 0);
        }
        __syncthreads();
    }

    // epilogue: C/D layout col = lane&15, row = (lane>>4)*4 + r
#pragma unroll
    for (int j = 0; j < 4; ++j) {
        const int col = n0 + wn * 64 + j * 16 + lane16;
        const float bv = bias[col];
#pragma unroll
        for (int i = 0; i < 4; ++i) {
            const int row = m0 + wm * 64 + i * 16 + kq * 4;
#pragma unroll
            for (int r = 0; r < 4; ++r)
                out[(size_t)(row + r) * OUT_F + col] = acc[i][j][r] + bv;
        }
    }
}

// ---------------------------------------------------------------------------
// Fallback fused kernel (used only if ws_size < 96 MB) — round-1 version
// ---------------------------------------------------------------------------
#define SA 72
#define SB 72
__global__ __launch_bounds__(256) void hqq_gemm_fused_kernel(
    const float* __restrict__ x, const int* __restrict__ Wp,
    const float* __restrict__ scale, const float* __restrict__ zero,
    const float* __restrict__ bias, float* __restrict__ out)
{
    __shared__ __align__(16) bf16 asmem[128 * SA];
    __shared__ __align__(16) bf16 bsmem[128 * SB];
    const int t = threadIdx.x, lane = t & 63, wave = t >> 6;
    const int lane16 = lane & 15, kq = lane >> 4;
    const int wm = wave >> 1, wn = wave & 1;
    const int n0 = blockIdx.x * 128, m0 = blockIdx.y * 128;
    floatx4 acc[4][4];
#pragma unroll
    for (int i = 0; i < 4; ++i)
#pragma unroll
        for (int j = 0; j < 4; ++j) acc[i][j] = (floatx4){0.f, 0.f, 0.f, 0.f};
    const int a_col4 = t & 15, a_row0 = t >> 4;
    const int b_nl = t >> 1, b_half = t & 1;
    for (int kt = 0; kt < IN_F / 64; ++kt) {
        const float* xp = x + (size_t)(m0 + a_row0) * IN_F + kt * 64 + a_col4 * 4;
#pragma unroll
        for (int p = 0; p < 8; ++p) {
            float4 v = *(const float4*)(xp + (size_t)(p * 16) * IN_F);
            bf16x4 b = { (bf16)v.x, (bf16)v.y, (bf16)v.z, (bf16)v.w };
            *(bf16x4*)&asmem[(a_row0 + p * 16) * SA + a_col4 * 4] = b;
        }
        {
            const int4 v = *(const int4*)(Wp + (size_t)(n0 + b_nl) * (IN_F / 8)
                                          + kt * 8 + b_half * 4);
            const int g = (n0 + b_nl) * (IN_F / 64) + kt;
            const float sc = scale[g], zp = zero[g];
            const bf16 hi = (bf16)((1.0f - zp) * sc), lo = (bf16)(0.0f - zp * sc);
            const int vals[4] = {v.x, v.y, v.z, v.w};
#pragma unroll
            for (int e = 0; e < 4; ++e) {
                bf16x8 w;
#pragma unroll
                for (int j = 0; j < 8; ++j) w[j] = ((vals[e] >> j) & 1) ? hi : lo;
                *(bf16x8*)&bsmem[b_nl * SB + b_half * 32 + e * 8] = w;
            }
        }
        __syncthreads();
#pragma unroll
        for (int ks = 0; ks < 2; ++ks) {
            bf16x8 af[4], bfr[4];
#pragma unroll
            for (int i = 0; i < 4; ++i)
                af[i] = *(const bf16x8*)&asmem[(wm * 64 + i * 16 + lane16) * SA + ks * 32 + kq * 8];
#pragma unroll
            for (int j = 0; j < 4; ++j)
                bfr[j] = *(const bf16x8*)&bsmem[(wn * 64 + j * 16 + lane16) * SB + ks * 32 + kq * 8];
#pragma unroll
            for (int i = 0; i < 4; ++i)
#pragma unroll
                for (int j = 0; j < 4; ++j)
                    acc[i][j] = __builtin_amdgcn_mfma_f32_16x16x32_bf16(af[i], bfr[j], acc[i][j], 0, 0, 0);
        }
        __syncthreads();
    }
#pragma unroll
    for (int j = 0; j < 4; ++j) {
        const int col = n0 + wn * 64 + j * 16 + lane16;
        const float bv = bias[col];
#pragma unroll
        for (int i = 0; i < 4; ++i) {
            const int row = m0 + wm * 64 + i * 16 + kq * 4;
#pragma unroll
            for (int r = 0; r < 4; ++r)
                out[(size_t)(row + r) * OUT_F + col] = acc[i][j][r] + bv;
        }
    }
}

// ---------------------------------------------------------------------------
extern "C" void kernel_launch(void* const* d_in, const int* in_sizes, int n_in,
                              void* d_out, int out_size, void* d_ws, size_t ws_size,
                              hipStream_t stream) {
    const float* x     = (const float*)d_in[0];
    const int*   Wp    = (const int*)d_in[1];
    const float* scale = (const float*)d_in[2];
    const float* zero  = (const float*)d_in[3];
    const float* bias  = (const float*)d_in[4];
    float*       out   = (float*)d_out;

    const int M = in_sizes[0] / IN_F;   // 8192
    const size_t need = (size_t)M * IN_F * 2 + (size_t)OUT_F * IN_F * 2;  // 96 MB

    if (ws_size >= need) {
        bf16* xb = (bf16*)d_ws;
        bf16* Wb = (bf16*)((char*)d_ws + (size_t)M * IN_F * 2);

        convert_x_kernel<<<(M * IN_F / 4) / 256, 256, 0, stream>>>(x, xb);
        dequant_w_kernel<<<(OUT_F * IN_F / 8) / 256, 256, 0, stream>>>(Wp, scale, zero, Wb);

        dim3 grid(OUT_F / 128, M / 128);   // (32, 64)
        bf16_gemm_bt_kernel<<<grid, 256, 0, stream>>>(xb, Wb, bias, out);
    } else {
        dim3 grid(OUT_F / 128, M / 128);
        hqq_gemm_fused_kernel<<<grid, 256, 0, stream>>>(x, Wp, scale, zero, bias, out);
    }
}

// Round 3
// 509.931 us; speedup vs baseline: 1.4131x; 1.0260x over previous
//
#include <hip/hip_runtime.h>
#include <hip/hip_bf16.h>

#define IN_F   4096
#define OUT_F  4096

typedef __bf16 bf16;
typedef __attribute__((ext_vector_type(8)))  __bf16 bf16x8;
typedef __attribute__((ext_vector_type(4)))  __bf16 bf16x4;
typedef __attribute__((ext_vector_type(4)))  float  floatx4;
typedef __attribute__((ext_vector_type(16))) float  floatx16;

// ---------------------------------------------------------------------------
// Merged pre-pass: blocks [0, nxb) convert x fp32->bf16 (float4/thread);
// blocks [nxb, ...) unpack+dequant W to bf16 row-major (N, K).
// ---------------------------------------------------------------------------
__global__ __launch_bounds__(256) void prep_kernel(
    const float* __restrict__ x,  bf16* __restrict__ xb,
    const int* __restrict__ Wp,   const float* __restrict__ scale,
    const float* __restrict__ zero, bf16* __restrict__ Wb, int nxb)
{
    if ((int)blockIdx.x < nxb) {
        const size_t i = (size_t)blockIdx.x * 256 + threadIdx.x;
        float4 v = ((const float4*)x)[i];
        bf16x4 b = { (bf16)v.x, (bf16)v.y, (bf16)v.z, (bf16)v.w };
        ((bf16x4*)xb)[i] = b;
    } else {
        const int tid = (blockIdx.x - nxb) * 256 + threadIdx.x;  // one packed byte-word
        const int n = tid >> 9;                  // / (IN_F/8)
        const int b = tid & 511;
        const int g = (n << 6) + (b >> 3);       // group = n*64 + k/64
        const float sc = scale[g];
        const float zp = zero[g];
        const bf16 hi = (bf16)((1.0f - zp) * sc);
        const bf16 lo = (bf16)((0.0f - zp) * sc);
        const int v = Wp[tid];
        bf16x8 w;
#pragma unroll
        for (int j = 0; j < 8; ++j) w[j] = ((v >> j) & 1) ? hi : lo;
        *(bf16x8*)&Wb[(size_t)tid * 8] = w;
    }
}

// ---------------------------------------------------------------------------
// Main GEMM: out(M,N) = A(M,K)bf16 @ B(N,K)^T + bias, fp32 out.
// m97 structure, 128x128x64 tiles, global_load_lds 16B staging with XOR
// swizzle on the per-lane GLOBAL address (LDS contract preserved),
// 32x32x16 MFMA (half the issue slots of 16x16x32 per FLOP).
// ---------------------------------------------------------------------------
__device__ __forceinline__ void gload_lds16(const void* g, void* l) {
    __builtin_amdgcn_global_load_lds(
        (const __attribute__((address_space(1))) unsigned int*)g,
        (__attribute__((address_space(3))) unsigned int*)l, 16, 0, 0);
}

__global__ __launch_bounds__(256) void bf16_gemm_bt_kernel(
    const bf16* __restrict__ A,     // (M, K) bf16
    const bf16* __restrict__ B,     // (N, K) bf16
    const float* __restrict__ bias, // (N,)
    float* __restrict__ out)        // (M, N) fp32
{
    __shared__ __align__(16) bf16 as[128 * 64];
    __shared__ __align__(16) bf16 bs[128 * 64];

    const int t      = threadIdx.x;
    const int lane   = t & 63;
    const int wave   = t >> 6;        // 0..3
    const int lane32 = lane & 31;
    const int half   = lane >> 5;     // 0..1
    const int wm     = wave >> 1;     // 64-row half
    const int wn     = wave & 1;      // 64-col half

    const int n0 = blockIdx.x * 128;
    const int m0 = blockIdx.y * 128;

    floatx16 acc[2][2];
#pragma unroll
    for (int i = 0; i < 2; ++i)
#pragma unroll
        for (int j = 0; j < 2; ++j)
#pragma unroll
            for (int r = 0; r < 16; ++r) acc[i][j][r] = 0.f;

    // staging: each wave covers 32 rows (4 issues x 8 rows)
    const int srow8 = lane >> 3;      // row within 8-row issue
    const int sunit = lane & 7;       // 16B unit within 64-wide row

    for (int kt = 0; kt < IN_F / 64; ++kt) {
#pragma unroll
        for (int i = 0; i < 4; ++i) {
            const int row   = wave * 32 + i * 8 + srow8;       // 0..127
            const int gunit = sunit ^ (row & 7);               // XOR swizzle
            gload_lds16(A + (size_t)(m0 + row) * IN_F + kt * 64 + gunit * 8,
                        &as[(wave * 32 + i * 8) * 64]);
            gload_lds16(B + (size_t)(n0 + row) * IN_F + kt * 64 + gunit * 8,
                        &bs[(wave * 32 + i * 8) * 64]);
        }
        __syncthreads();

        // 4 k-steps of 16; A frag: m=lane&31, k=(lane>>5)*8+j
#pragma unroll
        for (int s = 0; s < 4; ++s) {
            const int u = s * 2 + half;           // 16B unit index within row
            bf16x8 af[2], bfr[2];
#pragma unroll
            for (int i = 0; i < 2; ++i) {
                const int r = wm * 64 + i * 32 + lane32;
                af[i] = *(const bf16x8*)&as[r * 64 + (u ^ (r & 7)) * 8];
            }
#pragma unroll
            for (int j = 0; j < 2; ++j) {
                const int r = wn * 64 + j * 32 + lane32;
                bfr[j] = *(const bf16x8*)&bs[r * 64 + (u ^ (r & 7)) * 8];
            }
#pragma unroll
            for (int i = 0; i < 2; ++i)
#pragma unroll
                for (int j = 0; j < 2; ++j)
                    acc[i][j] = __builtin_amdgcn_mfma_f32_32x32x16_bf16(
                        af[i], bfr[j], acc[i][j], 0, 0, 0);
        }
        __syncthreads();
    }

    // epilogue: C/D layout col=lane&31, row=(reg&3)+8*(reg>>2)+4*(lane>>5)
#pragma unroll
    for (int j = 0; j < 2; ++j) {
        const int col = n0 + wn * 64 + j * 32 + lane32;
        const float bv = bias[col];
#pragma unroll
        for (int i = 0; i < 2; ++i) {
            const int rowbase = m0 + wm * 64 + i * 32 + 4 * half;
#pragma unroll
            for (int reg = 0; reg < 16; ++reg) {
                const int row = rowbase + (reg & 3) + 8 * (reg >> 2);
                out[(size_t)row * OUT_F + col] = acc[i][j][reg] + bv;
            }
        }
    }
}

// ---------------------------------------------------------------------------
// Fallback fused kernel (only if ws too small) — round-1 version
// ---------------------------------------------------------------------------
#define SA 72
#define SB 72
__global__ __launch_bounds__(256) void hqq_gemm_fused_kernel(
    const float* __restrict__ x, const int* __restrict__ Wp,
    const float* __restrict__ scale, const float* __restrict__ zero,
    const float* __restrict__ bias, float* __restrict__ out)
{
    __shared__ __align__(16) bf16 asmem[128 * SA];
    __shared__ __align__(16) bf16 bsmem[128 * SB];
    const int t = threadIdx.x, lane = t & 63, wave = t >> 6;
    const int lane16 = lane & 15, kq = lane >> 4;
    const int wm = wave >> 1, wn = wave & 1;
    const int n0 = blockIdx.x * 128, m0 = blockIdx.y * 128;
    floatx4 acc[4][4];
#pragma unroll
    for (int i = 0; i < 4; ++i)
#pragma unroll
        for (int j = 0; j < 4; ++j) acc[i][j] = (floatx4){0.f, 0.f, 0.f, 0.f};
    const int a_col4 = t & 15, a_row0 = t >> 4;
    const int b_nl = t >> 1, b_half = t & 1;
    for (int kt = 0; kt < IN_F / 64; ++kt) {
        const float* xp = x + (size_t)(m0 + a_row0) * IN_F + kt * 64 + a_col4 * 4;
#pragma unroll
        for (int p = 0; p < 8; ++p) {
            float4 v = *(const float4*)(xp + (size_t)(p * 16) * IN_F);
            bf16x4 b = { (bf16)v.x, (bf16)v.y, (bf16)v.z, (bf16)v.w };
            *(bf16x4*)&asmem[(a_row0 + p * 16) * SA + a_col4 * 4] = b;
        }
        {
            const int4 v = *(const int4*)(Wp + (size_t)(n0 + b_nl) * (IN_F / 8)
                                          + kt * 8 + b_half * 4);
            const int g = (n0 + b_nl) * (IN_F / 64) + kt;
            const float sc = scale[g], zp = zero[g];
            const bf16 hi = (bf16)((1.0f - zp) * sc), lo = (bf16)(0.0f - zp * sc);
            const int vals[4] = {v.x, v.y, v.z, v.w};
#pragma unroll
            for (int e = 0; e < 4; ++e) {
                bf16x8 w;
#pragma unroll
                for (int j = 0; j < 8; ++j) w[j] = ((vals[e] >> j) & 1) ? hi : lo;
                *(bf16x8*)&bsmem[b_nl * SB + b_half * 32 + e * 8] = w;
            }
        }
        __syncthreads();
#pragma unroll
        for (int ks = 0; ks < 2; ++ks) {
            bf16x8 af[4], bfr[4];
#pragma unroll
            for (int i = 0; i < 4; ++i)
                af[i] = *(const bf16x8*)&asmem[(wm * 64 + i * 16 + lane16) * SA + ks * 32 + kq * 8];
#pragma unroll
            for (int j = 0; j < 4; ++j)
                bfr[j] = *(const bf16x8*)&bsmem[(wn * 64 + j * 16 + lane16) * SB + ks * 32 + kq * 8];
#pragma unroll
            for (int i = 0; i < 4; ++i)
#pragma unroll
                for (int j = 0; j < 4; ++j)
                    acc[i][j] = __builtin_amdgcn_mfma_f32_16x16x32_bf16(af[i], bfr[j], acc[i][j], 0, 0, 0);
        }
        __syncthreads();
    }
#pragma unroll
    for (int j = 0; j < 4; ++j) {
        const int col = n0 + wn * 64 + j * 16 + lane16;
        const float bv = bias[col];
#pragma unroll
        for (int i = 0; i < 4; ++i) {
            const int row = m0 + wm * 64 + i * 16 + kq * 4;
#pragma unroll
            for (int r = 0; r < 4; ++r)
                out[(size_t)(row + r) * OUT_F + col] = acc[i][j][r] + bv;
        }
    }
}

// ---------------------------------------------------------------------------
extern "C" void kernel_launch(void* const* d_in, const int* in_sizes, int n_in,
                              void* d_out, int out_size, void* d_ws, size_t ws_size,
                              hipStream_t stream) {
    const float* x     = (const float*)d_in[0];
    const int*   Wp    = (const int*)d_in[1];
    const float* scale = (const float*)d_in[2];
    const float* zero  = (const float*)d_in[3];
    const float* bias  = (const float*)d_in[4];
    float*       out   = (float*)d_out;

    const int M = in_sizes[0] / IN_F;   // 8192
    const size_t need = (size_t)M * IN_F * 2 + (size_t)OUT_F * IN_F * 2;  // 96 MB

    if (ws_size >= need) {
        bf16* xb = (bf16*)d_ws;
        bf16* Wb = (bf16*)((char*)d_ws + (size_t)M * IN_F * 2);

        const int nxb = (M * IN_F / 4) / 256;            // x-convert blocks
        const int nwb = (OUT_F * IN_F / 8) / 256;        // dequant blocks
        prep_kernel<<<nxb + nwb, 256, 0, stream>>>(x, xb, Wp, scale, zero, Wb, nxb);

        dim3 grid(OUT_F / 128, M / 128);   // (32, 64)
        bf16_gemm_bt_kernel<<<grid, 256, 0, stream>>>(xb, Wb, bias, out);
    } else {
        dim3 grid(OUT_F / 128, M / 128);
        hqq_gemm_fused_kernel<<<grid, 256, 0, stream>>>(x, Wp, scale, zero, bias, out);
    }
}